// Round 5
// baseline (370.998 us; speedup 1.0000x reference)
//
#include <hip/hip_runtime.h>
#include <stdint.h>
#include <stddef.h>

// Problem constants
#define BN 16
#define CN 128
#define HN 56
#define WN 56
#define HWN 3136            // H*W
#define FN 9                // K*K deformation taps
#define DN 18               // 2*F offset channels
#define ON 512              // OUT
#define KN 1152             // F*C  (GEMM K)
#define MN 50176            // B*H*W (GEMM M)
#define MB 128              // m per fused block

typedef __bf16 bf16x8 __attribute__((ext_vector_type(8)));
typedef float f32x4 __attribute__((ext_vector_type(4)));

__device__ __forceinline__ unsigned short f2bf(float f) {
  unsigned int u = __builtin_bit_cast(unsigned int, f);
  u += 0x7fffu + ((u >> 16) & 1u);   // round-to-nearest-even
  return (unsigned short)(u >> 16);
}

// ---------------- Phase 0a: x fp32 [B,C,HW] -> xt bf16 [B,HW,C] ----------------
__global__ void k_transpose(const float* __restrict__ x, unsigned short* __restrict__ xt) {
  __shared__ float tile[32][33];
  const int b = blockIdx.z;
  const int hw0 = blockIdx.x * 32;   // 3136/32 = 98 exact
  const int c0 = blockIdx.y * 32;    // 128/32 = 4 exact
  const int tx = threadIdx.x & 31;
  const int ty = threadIdx.x >> 5;   // 0..7
  const float* xb = x + (size_t)b * CN * HWN;
  unsigned short* xtb = xt + (size_t)b * HWN * CN;
#pragma unroll
  for (int r = 0; r < 4; ++r)
    tile[ty + r * 8][tx] = xb[(size_t)(c0 + ty + r * 8) * HWN + hw0 + tx];
  __syncthreads();
#pragma unroll
  for (int r = 0; r < 4; ++r)
    xtb[(size_t)(hw0 + ty + r * 8) * CN + c0 + tx] = f2bf(tile[tx][ty + r * 8]);
}

// ---------------- Phase 0b: w_conv fp32 -> W2 bf16, FRAGMENT-PACKED -------------
// W2 chunk id cid = (kt2*32 + og)*64 + lane ; lane = quad*16 + r16.
// Chunk holds W[o = og*16 + r16][k = f*128 + hh*64 + H*32 + quad*8 .. +8],
// kt2 = ((2f+hh)*2+H). A wave's A-fragment load is then ONE dense 1 KiB read
// (R4 post-mortem: row-strided gather = 16 L2 segments per load instruction).
__global__ void k_wpack(const float* __restrict__ w, unsigned short* __restrict__ w2) {
  const int cid = blockIdx.x * 256 + threadIdx.x;   // 73728 chunks = 288*256
  const int lane = cid & 63;
  const int og = (cid >> 6) & 31;
  const int kt2 = cid >> 11;                        // 0..35
  const int quad = lane >> 4, r16 = lane & 15;
  const int o = og * 16 + r16;
  const int f = kt2 >> 2, hh = (kt2 >> 1) & 1, H = kt2 & 1;
  const int k = f * 128 + hh * 64 + H * 32 + quad * 8;
  const float* src = w + (size_t)o * KN + k;
  unsigned short ov[8];
#pragma unroll
  for (int q = 0; q < 8; ++q) ov[q] = f2bf(src[q]);
  *(uint4*)(w2 + (size_t)cid * 8) = *(const uint4*)ov;
}

// ---------------- Phase 1: per-pixel offset conv -> (ix,iy) per tap ------------
__global__ void k_offsets(const unsigned short* __restrict__ xt, const float* __restrict__ w_off,
                          const float* __restrict__ b_off, float2* __restrict__ ixy) {
  __shared__ float lwoff[DN * CN];
  __shared__ float lboff[DN];
  for (int i = threadIdx.x; i < DN * CN; i += 256) lwoff[i] = w_off[i];
  if (threadIdx.x < DN) lboff[threadIdx.x] = b_off[threadIdx.x];
  __syncthreads();

  const int m = blockIdx.x * 256 + threadIdx.x;  // 50176 = 196*256 exact
  const int b = m / HWN;
  const int hw = m - b * HWN;
  const int h = hw / WN;
  const int w = hw - h * WN;
  const unsigned short* xp = xt + (size_t)m * CN;
  float acc[DN];
#pragma unroll
  for (int d = 0; d < DN; ++d) acc[d] = lboff[d];
  for (int c = 0; c < CN; c += 8) {
    bf16x8 xv = *(const bf16x8*)(xp + c);
    float xf[8];
#pragma unroll
    for (int q = 0; q < 8; ++q) xf[q] = (float)xv[q];
#pragma unroll
    for (int d = 0; d < DN; ++d) {
      float4 w0 = *(const float4*)(lwoff + d * CN + c);      // uniform -> broadcast
      float4 w1 = *(const float4*)(lwoff + d * CN + c + 4);
      acc[d] += xf[0] * w0.x + xf[1] * w0.y + xf[2] * w0.z + xf[3] * w0.w
              + xf[4] * w1.x + xf[5] * w1.y + xf[6] * w1.z + xf[7] * w1.w;
    }
  }
  const float scale = 2.0f / 56.0f;
  const float bx = (2.0f * w + 1.0f) / (float)WN - 1.0f;
  const float by = (2.0f * h + 1.0f) / (float)HN - 1.0f;
#pragma unroll
  for (int f = 0; f < FN; ++f) {
    float gx = bx + acc[2 * f] * scale;
    float gy = by + acc[2 * f + 1] * scale;
    float ixv = ((gx + 1.0f) * (float)WN - 1.0f) * 0.5f;
    float iyv = ((gy + 1.0f) * (float)HN - 1.0f) * 0.5f;
    ixy[(size_t)m * FN + f] = make_float2(ixv, iyv);
  }
}

// ---------------- Phase 2: FUSED sample + GEMM -----------------------------------
// out[o,m] = sum_k W[o,k]*S[m,k] + bias[o], S built on the fly.
// f-loop (9 iters): tap f's TWO K-tiles (ch 0..63 / 64..127) share bilinear
// weights -> compute once per f, build both halves, ONE barrier per 2 K-tiles.
// T14 ordering per iter: issue gathers -> A-loads + 64 MFMA -> finish build.
// A: dense 1 KiB fragment loads from packed W2 (L2-resident).
// B: 32 KB double-tile (two 16 KB chunk-XOR-swizzled halves), double-buffered.
__global__ __launch_bounds__(512, 2) void k_fused(const unsigned short* __restrict__ W2,
                                                  const unsigned short* __restrict__ xt,
                                                  const float2* __restrict__ ixy,
                                                  const float* __restrict__ bias,
                                                  float* __restrict__ out) {
  __shared__ __align__(16) char smem[74752];
  // buf0 @0 (hh0 16K, hh1 16K), buf1 @32768, lixy @65536 (9216 B)
  float2* lixy = (float2*)(smem + 65536);
  const int tid = threadIdx.x;
  const int wave = tid >> 6;
  const int lane = tid & 63;
  const int quad = lane >> 4;
  const int r16 = lane & 15;
  const int wm = wave >> 1;          // 0..3 (o, 128 rows each)
  const int wn = wave & 1;           // 0..1 (m, 64 cols each)

  // XCD-bijective swizzle (392 = 8*49): m-neighbors share an XCD -> corner
  // reads of adjacent spatial rows hit the same L2.
  const int bid = blockIdx.x;
  const int wgid = (bid & 7) * 49 + (bid >> 3);
  const int m0 = wgid * MB;

  for (int i = tid; i < MB * FN; i += 512) lixy[i] = ixy[(size_t)m0 * FN + i];

  // build-thread constants: thread -> (m-local, 16-ch slice)
  const int bm = tid >> 2;            // 0..127
  const int bc = (tid & 3) * 16;      // ch offset within a 64-ch half
  const int gm = m0 + bm;
  const int bb = gm / HWN;
  const unsigned short* xb = xt + (size_t)bb * HWN * CN + bc;

  f32x4 acc[8][4];
#pragma unroll
  for (int i = 0; i < 8; ++i)
#pragma unroll
    for (int j = 0; j < 4; ++j) acc[i][j] = (f32x4){0.f, 0.f, 0.f, 0.f};

  const int rsw = r16 & 7;
  const int b_row = (wn * 64 + r16) * 128;   // byte row base in a B half-tile
  // A fragment base: lane's 16B within the 1 KiB chunk of (kt2, og=wm*8+i)
  const char* aT = (const char*)W2 + (size_t)(wm * 8) * 1024 + lane * 16;

  // per-f bilinear state (shared by both K-tiles of the tap)
  float w00, w01, w10, w11;
  int r00, r01, r10, r11;
  bf16x8 gA0, gA1, gB0, gB1, gC0, gC1, gD0, gD1;

#define WCOMP(F) do {                                                            \
    const float2 p_ = lixy[bm * FN + (F)];                                       \
    const float x0f = floorf(p_.x), y0f = floorf(p_.y);                          \
    const float wx1 = p_.x - x0f, wy1 = p_.y - y0f;                              \
    const float wx0 = 1.0f - wx1, wy0 = 1.0f - wy1;                              \
    const int x0 = (int)x0f, y0 = (int)y0f, x1 = x0 + 1, y1 = y0 + 1;            \
    const bool vx0 = (x0 >= 0) & (x0 < WN), vx1 = (x1 >= 0) & (x1 < WN);         \
    const bool vy0 = (y0 >= 0) & (y0 < HN), vy1 = (y1 >= 0) & (y1 < HN);         \
    w00 = wy0 * wx0 * ((vy0 & vx0) ? 1.0f : 0.0f);                               \
    w01 = wy0 * wx1 * ((vy0 & vx1) ? 1.0f : 0.0f);                               \
    w10 = wy1 * wx0 * ((vy1 & vx0) ? 1.0f : 0.0f);                               \
    w11 = wy1 * wx1 * ((vy1 & vx1) ? 1.0f : 0.0f);                               \
    const int x0c = min(max(x0, 0), WN - 1), x1c = min(max(x1, 0), WN - 1);      \
    const int y0c = min(max(y0, 0), HN - 1), y1c = min(max(y1, 0), HN - 1);      \
    r00 = (y0c * WN + x0c) * CN; r01 = (y0c * WN + x1c) * CN;                    \
    r10 = (y1c * WN + x0c) * CN; r11 = (y1c * WN + x1c) * CN;                    \
  } while (0)

#define GISSUE(HH) do {                                                          \
    const unsigned short* cp_ = xb + (HH) * 64;                                  \
    gA0 = *(const bf16x8*)(cp_ + r00); gA1 = *(const bf16x8*)(cp_ + r00 + 8);    \
    gB0 = *(const bf16x8*)(cp_ + r01); gB1 = *(const bf16x8*)(cp_ + r01 + 8);    \
    gC0 = *(const bf16x8*)(cp_ + r10); gC1 = *(const bf16x8*)(cp_ + r10 + 8);    \
    gD0 = *(const bf16x8*)(cp_ + r11); gD1 = *(const bf16x8*)(cp_ + r11 + 8);    \
  } while (0)

  // lerp + v_cvt_pk_bf16_f32 pack + swizzled ds_write (chunk c stored at c^(bm&7))
#define GFINISH(DSTOFF) do {                                                     \
    unsigned int plo[4], phi[4];                                                 \
    _Pragma("unroll") for (int q2 = 0; q2 < 4; ++q2) {                           \
      float l0 = w00 * (float)gA0[2 * q2] + w01 * (float)gB0[2 * q2]             \
               + w10 * (float)gC0[2 * q2] + w11 * (float)gD0[2 * q2];            \
      float l1 = w00 * (float)gA0[2 * q2 + 1] + w01 * (float)gB0[2 * q2 + 1]     \
               + w10 * (float)gC0[2 * q2 + 1] + w11 * (float)gD0[2 * q2 + 1];    \
      asm("v_cvt_pk_bf16_f32 %0, %1, %2" : "=v"(plo[q2]) : "v"(l0), "v"(l1));    \
      float h0 = w00 * (float)gA1[2 * q2] + w01 * (float)gB1[2 * q2]             \
               + w10 * (float)gC1[2 * q2] + w11 * (float)gD1[2 * q2];            \
      float h1 = w00 * (float)gA1[2 * q2 + 1] + w01 * (float)gB1[2 * q2 + 1]     \
               + w10 * (float)gC1[2 * q2 + 1] + w11 * (float)gD1[2 * q2 + 1];    \
      asm("v_cvt_pk_bf16_f32 %0, %1, %2" : "=v"(phi[q2]) : "v"(h0), "v"(h1));    \
    }                                                                            \
    const int c0_ = (tid & 3) * 2;                                               \
    *(uint4*)(smem + (DSTOFF) + bm * 128 + ((c0_ ^ (bm & 7)) * 16)) =            \
        *(const uint4*)plo;                                                      \
    *(uint4*)(smem + (DSTOFF) + bm * 128 + (((c0_ + 1) ^ (bm & 7)) * 16)) =      \
        *(const uint4*)phi;                                                      \
  } while (0)

  // dense A-fragment loads: one contiguous 1 KiB per (i_, kt2)
#define LOADA(AV, KT2) do {                                                      \
    _Pragma("unroll") for (int i_ = 0; i_ < 8; ++i_)                             \
      AV[i_] = *(const bf16x8*)(aT + (size_t)(KT2) * 32768 + i_ * 1024);         \
  } while (0)

#define ABM(PARB, H, AV) do {                                                    \
    const char* bp_ = smem + (PARB) + b_row;                                     \
    bf16x8 bv[4];                                                                \
    _Pragma("unroll") for (int j_ = 0; j_ < 4; ++j_)                             \
      bv[j_] = *(const bf16x8*)(bp_ + j_ * 16 * 128 + ((((H) * 4 + quad) ^ rsw) * 16)); \
    __builtin_amdgcn_s_setprio(1);                                               \
    _Pragma("unroll") for (int i_ = 0; i_ < 8; ++i_)                             \
    _Pragma("unroll") for (int j_ = 0; j_ < 4; ++j_)                             \
      acc[i_][j_] = __builtin_amdgcn_mfma_f32_16x16x32_bf16(AV[i_], bv[j_],      \
                                                            acc[i_][j_], 0, 0, 0); \
    __builtin_amdgcn_s_setprio(0);                                               \
  } while (0)

  __syncthreads();            // lixy ready
  // prologue: build tap 0's double-tile into buf0
  WCOMP(0);
  GISSUE(0); GFINISH(0);
  GISSUE(1); GFINISH(16384);
  __syncthreads();

#pragma unroll 1
  for (int f = 0; f < 9; ++f) {
    const int CUR = (f & 1) * 32768;
    const int NXT = 32768 - CUR;
    const int kt2b = f * 4;
    bf16x8 a0[8], a1[8];
    if (f < 8) { WCOMP(f + 1); GISSUE(0); }    // gathers in flight under MFMA
    // K-tile 2f (ch-half hh=0)
    LOADA(a0, kt2b + 0);
    LOADA(a1, kt2b + 1);
    ABM(CUR + 0, 0, a0);
    ABM(CUR + 0, 1, a1);
    if (f < 8) { GFINISH(NXT + 0); GISSUE(1); }
    // K-tile 2f+1 (ch-half hh=1)
    LOADA(a0, kt2b + 2);
    LOADA(a1, kt2b + 3);
    ABM(CUR + 16384, 0, a0);
    ABM(CUR + 16384, 1, a1);
    if (f < 8) { GFINISH(NXT + 16384); }
    __syncthreads();   // NXT visible; WAR on CUR before overwrite next iter
  }

  // Epilogue: 16 FULLY-UNROLLED rounds (rule #20: runtime acc indices demote
  // the accumulator to scratch) of 32 o-rows x 128 m fp32 staged in LDS
  // (stride 132 breaks quad-row bank alias), then full float4 lines out.
  // C/D layout: col(m)=r16, row(o)=quad*4+reg.
  float* lout = (float*)smem;
  const int LSTR = 132;
#pragma unroll
  for (int ob = 0; ob < 16; ++ob) {
    __syncthreads();
    if (wm == (ob >> 2)) {
#pragma unroll
      for (int il = 0; il < 2; ++il) {
        const int i = (ob & 3) * 2 + il;
#pragma unroll
        for (int j = 0; j < 4; ++j) {
          f32x4 v = acc[i][j];
          const int col = wn * 64 + j * 16 + r16;
          const int rb = il * 16 + quad * 4;
          lout[(rb + 0) * LSTR + col] = v[0];
          lout[(rb + 1) * LSTR + col] = v[1];
          lout[(rb + 2) * LSTR + col] = v[2];
          lout[(rb + 3) * LSTR + col] = v[3];
        }
      }
    }
    __syncthreads();
#pragma unroll
    for (int tl = 0; tl < 2; ++tl) {
      const int idx = tl * 512 + tid;       // 1024 f4 = 32 rows x 32 f4
      const int orow = idx >> 5, c4 = idx & 31;
      float4 v = *(const float4*)(lout + orow * LSTR + c4 * 4);
      const int o = ob * 32 + orow;
      const float bv = bias[o];
      v.x += bv; v.y += bv; v.z += bv; v.w += bv;
      const int p = m0 + c4 * 4;
      const int bidx = p / HWN;             // 3136 % 4 == 0 -> no b straddle
      const int hw = p - bidx * HWN;
      *(float4*)(out + (size_t)bidx * ON * HWN + (size_t)o * HWN + hw) = v;
    }
  }
#undef WCOMP
#undef GISSUE
#undef GFINISH
#undef LOADA
#undef ABM
}

extern "C" void kernel_launch(void* const* d_in, const int* in_sizes, int n_in,
                              void* d_out, int out_size, void* d_ws, size_t ws_size,
                              hipStream_t stream) {
  const float* x = (const float*)d_in[0];       // [16,128,56,56]
  const float* w_off = (const float*)d_in[1];   // [18,128]
  const float* b_off = (const float*)d_in[2];   // [18]
  const float* w_conv = (const float*)d_in[3];  // [512,1152]
  const float* b_conv = (const float*)d_in[4];  // [512]
  float* out = (float*)d_out;                   // [16,512,56,56] fp32

  // workspace layout (16B aligned):
  //   xt  : bf16 [B,HW,C]      12,845,056 B @ 0
  //   W2  : bf16 packed         1,179,648 B @ 12,845,056
  //   ixy : float2 [M,F]        3,612,672 B @ 14,024,704   (total ~17.6 MB)
  char* ws = (char*)d_ws;
  unsigned short* xt = (unsigned short*)(ws);
  unsigned short* W2 = (unsigned short*)(ws + 12845056);
  float2* ixy = (float2*)(ws + 14024704);

  k_transpose<<<dim3(98, 4, 16), 256, 0, stream>>>(x, xt);
  k_wpack<<<dim3(288), 256, 0, stream>>>(w_conv, W2);
  k_offsets<<<dim3(196), 256, 0, stream>>>(xt, w_off, b_off, ixy);
  k_fused<<<dim3(392), 512, 0, stream>>>(W2, xt, ixy, b_conv, out);
}

// Round 6
// 249.527 us; speedup vs baseline: 1.4868x; 1.4868x over previous
//
#include <hip/hip_runtime.h>
#include <stdint.h>
#include <stddef.h>

// Problem constants
#define BN 16
#define CN 128
#define HN 56
#define WN 56
#define HWN 3136            // H*W
#define FN 9                // K*K deformation taps
#define DN 18               // 2*F offset channels
#define ON 512              // OUT
#define KN 1152             // F*C  (GEMM K)
#define MN 50176            // B*H*W (GEMM M)

typedef __bf16 bf16x8 __attribute__((ext_vector_type(8)));
typedef float f32x4 __attribute__((ext_vector_type(4)));

__device__ __forceinline__ unsigned short f2bf(float f) {
  unsigned int u = __builtin_bit_cast(unsigned int, f);
  u += 0x7fffu + ((u >> 16) & 1u);   // round-to-nearest-even
  return (unsigned short)(u >> 16);
}

__device__ __forceinline__ void gload_lds16(const void* g, void* l) {
  __builtin_amdgcn_global_load_lds(
      (const __attribute__((address_space(1))) unsigned int*)g,
      (__attribute__((address_space(3))) unsigned int*)l, 16, 0, 0);
}

// ---------------- Phase 0a: x fp32 [B,C,HW] -> xt bf16 [B,HW,C] ----------------
__global__ void k_transpose(const float* __restrict__ x, unsigned short* __restrict__ xt) {
  __shared__ float tile[32][33];
  const int b = blockIdx.z;
  const int hw0 = blockIdx.x * 32;   // 3136/32 = 98 exact
  const int c0 = blockIdx.y * 32;    // 128/32 = 4 exact
  const int tx = threadIdx.x & 31;
  const int ty = threadIdx.x >> 5;   // 0..7
  const float* xb = x + (size_t)b * CN * HWN;
  unsigned short* xtb = xt + (size_t)b * HWN * CN;
#pragma unroll
  for (int r = 0; r < 4; ++r)
    tile[ty + r * 8][tx] = xb[(size_t)(c0 + ty + r * 8) * HWN + hw0 + tx];
  __syncthreads();
#pragma unroll
  for (int r = 0; r < 4; ++r)
    xtb[(size_t)(hw0 + ty + r * 8) * CN + c0 + tx] = f2bf(tile[tx][ty + r * 8]);
}

// ---------------- Phase 1: k_prep = fast offsets + wconv cast (merged) ---------
// R5 post-mortem (by subtraction across R0/R4/R5 pipelines): old k_offsets cost
// ~90-100 us despite 231 MFLOP / 16 MB — grid 196 (<=1 wave/SIMD), 64-segment
// scattered row reads, no TLP. Rewrite: 392 blocks x 128 thr; xt tile staged
// into LDS with COALESCED 16B global loads (consecutive tid -> consecutive 16B),
// padded 272B rows; each thread then dots its own m-row from LDS (w_off
// broadcast-read from LDS, uniform addresses). Arithmetic order identical to
// the old kernel (same absmax). wconv bf16 cast rides along as blocks >= 392
// (independent work, one fewer kernel boundary).
__global__ __launch_bounds__(128) void k_prep(const unsigned short* __restrict__ xt,
                                              const float* __restrict__ w_off,
                                              const float* __restrict__ b_off,
                                              const float4* __restrict__ wconv,
                                              ushort4* __restrict__ wb,
                                              float2* __restrict__ ixy) {
  __shared__ __align__(16) char smem[44128];  // [128 rows x 272B] xt + 9216B woff + boff
  const int tid = threadIdx.x;
  if (blockIdx.x >= 392) {
    const int i = (blockIdx.x - 392) * 128 + tid;   // 147456 f4 = 1152*128 exact
    float4 v = wconv[i];
    ushort4 o;
    o.x = f2bf(v.x); o.y = f2bf(v.y); o.z = f2bf(v.z); o.w = f2bf(v.w);
    wb[i] = o;
    return;
  }
  float* lwoff = (float*)(smem + 34816);
  float* lboff = (float*)(smem + 34816 + 9216);
  const int m0 = blockIdx.x * 128;                  // 392*128 = 50176 exact

  // stage xt[m0..m0+128)[0..128c) -> LDS rows of 272B (256 data + 16 pad)
  const unsigned short* gsrc = xt + (size_t)m0 * CN;
#pragma unroll
  for (int p = 0; p < 16; ++p) {
    const int s = p * 128 + tid;                    // 2048 16B chunks
    uint4 v = *(const uint4*)(gsrc + s * 8);
    *(uint4*)(smem + (s >> 4) * 272 + (s & 15) * 16) = v;
  }
  for (int i = tid; i < DN * CN / 4; i += 128)
    ((float4*)lwoff)[i] = ((const float4*)w_off)[i];
  if (tid < DN) lboff[tid] = b_off[tid];
  __syncthreads();

  const int m = m0 + tid;
  const int b = m / HWN;
  const int hw = m - b * HWN;
  const int h = hw / WN;
  const int w = hw - h * WN;

  float acc[DN];
#pragma unroll
  for (int d = 0; d < DN; ++d) acc[d] = lboff[d];
  const char* rowp = smem + tid * 272;
#pragma unroll
  for (int j = 0; j < 16; ++j) {
    bf16x8 xv = *(const bf16x8*)(rowp + j * 16);
    float xf[8];
#pragma unroll
    for (int q = 0; q < 8; ++q) xf[q] = (float)xv[q];
#pragma unroll
    for (int d = 0; d < DN; ++d) {
      const float* wr = lwoff + d * CN + j * 8;     // uniform -> broadcast
      acc[d] += xf[0] * wr[0] + xf[1] * wr[1] + xf[2] * wr[2] + xf[3] * wr[3]
              + xf[4] * wr[4] + xf[5] * wr[5] + xf[6] * wr[6] + xf[7] * wr[7];
    }
  }
  const float scale = 2.0f / 56.0f;
  const float bx = (2.0f * w + 1.0f) / (float)WN - 1.0f;
  const float by = (2.0f * h + 1.0f) / (float)HN - 1.0f;
#pragma unroll
  for (int f = 0; f < FN; ++f) {
    float gx = bx + acc[2 * f] * scale;
    float gy = by + acc[2 * f + 1] * scale;
    float ixv = ((gx + 1.0f) * (float)WN - 1.0f) * 0.5f;
    float iyv = ((gy + 1.0f) * (float)HN - 1.0f) * 0.5f;
    ixy[(size_t)m * FN + f] = make_float2(ixv, iyv);
  }
}

// ---------------- Phase 2: bilinear sample (bf16 in) -> S bf16 [M, K] ----------
// mf-major thread order: all 9 taps of a pixel in the same block -> corner reads
// overlap in L1/L2.
__global__ void k_sample(const unsigned short* __restrict__ xt, const float2* __restrict__ ixy,
                         unsigned short* __restrict__ S) {
  const int g = blockIdx.x * 256 + threadIdx.x;  // 50176*9*8 = 14112*256 exact
  const int cc = g & 7;           // 16-channel chunk
  const int mf = g >> 3;          // m*9 + f
  const int m = mf / FN;
  const int f = mf - m * FN;
  const int b = m / HWN;

  const float2 p = ixy[mf];
  const float ix = p.x, iy = p.y;
  const float x0f = floorf(ix), y0f = floorf(iy);
  const float wx1 = ix - x0f, wy1 = iy - y0f;
  const float wx0 = 1.0f - wx1, wy0 = 1.0f - wy1;
  const int x0 = (int)x0f, y0 = (int)y0f;
  const int x1 = x0 + 1, y1 = y0 + 1;
  const bool vx0 = (x0 >= 0) & (x0 < WN), vx1 = (x1 >= 0) & (x1 < WN);
  const bool vy0 = (y0 >= 0) & (y0 < HN), vy1 = (y1 >= 0) & (y1 < HN);
  const float w00 = wy0 * wx0 * ((vy0 & vx0) ? 1.0f : 0.0f);
  const float w01 = wy0 * wx1 * ((vy0 & vx1) ? 1.0f : 0.0f);
  const float w10 = wy1 * wx0 * ((vy1 & vx0) ? 1.0f : 0.0f);
  const float w11 = wy1 * wx1 * ((vy1 & vx1) ? 1.0f : 0.0f);
  const int x0c = min(max(x0, 0), WN - 1), x1c = min(max(x1, 0), WN - 1);
  const int y0c = min(max(y0, 0), HN - 1), y1c = min(max(y1, 0), HN - 1);

  const unsigned short* bp = xt + (size_t)b * HWN * CN + cc * 16;
  const bf16x8* p00 = (const bf16x8*)(bp + (size_t)(y0c * WN + x0c) * CN);
  const bf16x8* p01 = (const bf16x8*)(bp + (size_t)(y0c * WN + x1c) * CN);
  const bf16x8* p10 = (const bf16x8*)(bp + (size_t)(y1c * WN + x0c) * CN);
  const bf16x8* p11 = (const bf16x8*)(bp + (size_t)(y1c * WN + x1c) * CN);
  bf16x8 a0 = p00[0], a1 = p00[1];
  bf16x8 b0 = p01[0], b1 = p01[1];
  bf16x8 c0 = p10[0], c1 = p10[1];
  bf16x8 d0 = p11[0], d1 = p11[1];

  unsigned short ov[16];
#pragma unroll
  for (int q = 0; q < 8; ++q) {
    float lo = w00 * (float)a0[q] + w01 * (float)b0[q] + w10 * (float)c0[q] + w11 * (float)d0[q];
    float hi = w00 * (float)a1[q] + w01 * (float)b1[q] + w10 * (float)c1[q] + w11 * (float)d1[q];
    ov[q] = f2bf(lo);
    ov[q + 8] = f2bf(hi);
  }
  uint4* dst = (uint4*)(S + (size_t)m * KN + f * CN + cc * 16);
  dst[0] = *(const uint4*)(ov);
  dst[1] = *(const uint4*)(ov + 8);
}

// ---------------- Phase 3: GEMM  out[o,m] = sum_k Wb[o,k]*S[m,k] + bias[o] ------
// 128x128 tile, BK=64, XOR-swizzled LDS, single-buffer (best measured: 81.6 us),
// XCD-aware 1-D grid: the 4 o-tiles of one p-tile land on the SAME XCD.
__global__ __launch_bounds__(256) void k_gemm(const unsigned short* __restrict__ Wb,
                                              const unsigned short* __restrict__ S,
                                              const float* __restrict__ bias,
                                              float* __restrict__ out) {
  __shared__ __align__(16) char smem[32768];
  unsigned short* lw = (unsigned short*)smem;            // 16 KB: W tile [128 o][64 k]
  unsigned short* ls = (unsigned short*)(smem + 16384);  // 16 KB: S tile [128 m][64 k]
  const int tid = threadIdx.x;
  const int wave = tid >> 6;
  const int lane = tid & 63;
  const int quad = lane >> 4;
  const int r16 = lane & 15;
  const int bid = blockIdx.x;                 // 1568 = 4 o-tiles x 392 p-tiles
  const int ot = (bid >> 3) & 3;
  const int pt = (bid & 7) + ((bid >> 5) << 3);
  const int o0 = ot * 128;
  const int p0 = pt * 128;
  const int wrow = wave >> 1;       // o-dim wave
  const int wcol = wave & 1;        // m-dim wave

  f32x4 acc[4][4];
#pragma unroll
  for (int i = 0; i < 4; ++i)
#pragma unroll
    for (int j = 0; j < 4; ++j) acc[i][j] = (f32x4){0.f, 0.f, 0.f, 0.f};

  // staging: slot s = r*256 + tid -> LDS 16B chunk s; row = s/8, chunk-in-row = s%8.
  // swizzle: LDS[row][ch] holds global chunk (ch ^ (row&7)).
  const int row0 = tid >> 3;                              // 0..31
  const int swc = (((tid & 7) ^ (row0 & 7))) * 8;         // swizzled col (shorts)
  const unsigned short* gw = Wb + (size_t)(o0 + row0) * KN + swc;
  const unsigned short* gs = S + (size_t)(p0 + row0) * KN + swc;
  unsigned short* lwd = lw + wave * 512;   // wave-uniform LDS base (shorts)
  unsigned short* lsd = ls + wave * 512;

  // reader: fragment row = wrow*64+i*16+r16 (row&7 == r16&7),
  // wanted chunk c = quad + h*4 -> LDS chunk c ^ (r16&7)
  const int rsw = r16 & 7;
  const int ch0 = (quad ^ rsw) * 8;                 // h=0 chunk offset (shorts)
  const int ch1 = ((quad ^ rsw) ^ 4) * 8;           // h=1
  const unsigned short* aw = lw + (wrow * 64 + r16) * 64;
  const unsigned short* bs = ls + (wcol * 64 + r16) * 64;

  for (int kt = 0; kt < KN / 64; ++kt) {
#pragma unroll
    for (int r = 0; r < 4; ++r) {
      gload_lds16(gw + (size_t)r * 32 * KN, lwd + r * 2048);
      gload_lds16(gs + (size_t)r * 32 * KN, lsd + r * 2048);
    }
    gw += 64; gs += 64;
    __syncthreads();
#pragma unroll
    for (int h = 0; h < 2; ++h) {
      const int ch = h ? ch1 : ch0;
      bf16x8 afr[4], bfr[4];
#pragma unroll
      for (int i = 0; i < 4; ++i) afr[i] = *(const bf16x8*)(aw + i * 16 * 64 + ch);
#pragma unroll
      for (int j = 0; j < 4; ++j) bfr[j] = *(const bf16x8*)(bs + j * 16 * 64 + ch);
#pragma unroll
      for (int i = 0; i < 4; ++i)
#pragma unroll
        for (int j = 0; j < 4; ++j)
          acc[i][j] = __builtin_amdgcn_mfma_f32_16x16x32_bf16(afr[i], bfr[j], acc[i][j], 0, 0, 0);
    }
    __syncthreads();
  }

  // Epilogue: stage 64 o-rows x 128 p-cols fp32 in smem (32 KB), write full lines.
  // C/D layout: col(m)=r16, row(o)=quad*4+reg.
  float* lout = (float*)smem;
  for (int half = 0; half < 2; ++half) {
    __syncthreads();
    if (wrow == half) {
#pragma unroll
      for (int i = 0; i < 4; ++i) {
        const int orow = i * 16 + quad * 4;
#pragma unroll
        for (int j = 0; j < 4; ++j) {
          const int col = wcol * 64 + j * 16 + r16;
          lout[(orow + 0) * 128 + col] = acc[i][j][0];
          lout[(orow + 1) * 128 + col] = acc[i][j][1];
          lout[(orow + 2) * 128 + col] = acc[i][j][2];
          lout[(orow + 3) * 128 + col] = acc[i][j][3];
        }
      }
    }
    __syncthreads();
#pragma unroll
    for (int t = 0; t < 8; ++t) {
      const int idx = t * 256 + tid;        // 2048 float4s = 64 rows x 32 f4/row
      const int orow = idx >> 5;
      const int c4 = idx & 31;
      float4 v = ((const float4*)lout)[idx];
      const int o = o0 + half * 64 + orow;
      const float bv = bias[o];
      v.x += bv; v.y += bv; v.z += bv; v.w += bv;
      const int p = p0 + c4 * 4;
      const int bidx = p / HWN;             // 3136 % 4 == 0 -> float4 never straddles b
      const int hw = p - bidx * HWN;
      *(float4*)(out + (size_t)bidx * ON * HWN + (size_t)o * HWN + hw) = v;
    }
  }
}

extern "C" void kernel_launch(void* const* d_in, const int* in_sizes, int n_in,
                              void* d_out, int out_size, void* d_ws, size_t ws_size,
                              hipStream_t stream) {
  const float* x = (const float*)d_in[0];       // [16,128,56,56]
  const float* w_off = (const float*)d_in[1];   // [18,128]
  const float* b_off = (const float*)d_in[2];   // [18]
  const float* w_conv = (const float*)d_in[3];  // [512,1152]
  const float* b_conv = (const float*)d_in[4];  // [512]
  float* out = (float*)d_out;                   // [16,512,56,56] fp32

  // workspace layout (16B aligned):
  //   xt  : bf16 [B,HW,C]      12,845,056 B @ 0
  //   S   : bf16 [M,K]        115,605,504 B @ 12,845,056
  //   Wb  : bf16 [512,1152]     1,179,648 B @ 128,450,560
  //   ixy : float2 [M,F]        3,612,672 B @ 129,630,208   (total ~133.2 MB)
  char* ws = (char*)d_ws;
  unsigned short* xt = (unsigned short*)(ws);
  unsigned short* S = (unsigned short*)(ws + 12845056);
  unsigned short* Wb = (unsigned short*)(ws + 128450560);
  float2* ixy = (float2*)(ws + 129630208);

  k_transpose<<<dim3(98, 4, 16), 256, 0, stream>>>(x, xt);
  k_prep<<<dim3(1544), 128, 0, stream>>>(xt, w_off, b_off, (const float4*)w_conv,
                                         (ushort4*)Wb, ixy);
  k_sample<<<dim3(14112), 256, 0, stream>>>(xt, ixy, S);
  k_gemm<<<dim3(1568), 256, 0, stream>>>(Wb, S, b_conv, out);
}

// Round 7
// 246.352 us; speedup vs baseline: 1.5060x; 1.0129x over previous
//
#include <hip/hip_runtime.h>
#include <stdint.h>
#include <stddef.h>

// Problem constants
#define BN 16
#define CN 128
#define HN 56
#define WN 56
#define HWN 3136            // H*W
#define FN 9                // K*K deformation taps
#define DN 18               // 2*F offset channels
#define ON 512              // OUT
#define KN 1152             // F*C  (GEMM K)
#define MN 50176            // B*H*W (GEMM M)

typedef __bf16 bf16x8 __attribute__((ext_vector_type(8)));
typedef float f32x4 __attribute__((ext_vector_type(4)));

__device__ __forceinline__ unsigned short f2bf(float f) {
  unsigned int u = __builtin_bit_cast(unsigned int, f);
  u += 0x7fffu + ((u >> 16) & 1u);   // round-to-nearest-even
  return (unsigned short)(u >> 16);
}

__device__ __forceinline__ void gload_lds16(const void* g, void* l) {
  __builtin_amdgcn_global_load_lds(
      (const __attribute__((address_space(1))) unsigned int*)g,
      (__attribute__((address_space(3))) unsigned int*)l, 16, 0, 0);
}

// ---------------- Phase 1: k_prep2 = transpose + offsets + wconv (one kernel) ---
// R6 post-mortem: k_offsets rewrite was a NULL -> by subtraction across the
// R0/R4/R5/R6 pipeline compositions, k_transpose was the ~100 us sink (2-byte
// scalar stores, 6272 tiny blocks). Here the transpose is folded in:
//  - read x fp32 coalesced (lane = hw, 256 B/wave per c-row),
//  - f2bf once -> ds_write_b128 into [128 m][272 B] LDS tile (16B-aligned rows),
//  - offsets dot consumes fp32 x directly (reference uses fp32 x too),
//  - one barrier, then bulk LDS->global xt write at 16 B/lane, fully coalesced.
// xt values are bit-identical to the old k_transpose (same f2bf), so k_sample
// and k_gemm see identical inputs. Blocks >= 392 do the wconv bf16 cast.
__global__ __launch_bounds__(128) void k_prep2(const float* __restrict__ x,
                                               const float* __restrict__ w_off,
                                               const float* __restrict__ b_off,
                                               const float4* __restrict__ wconv,
                                               ushort4* __restrict__ wb,
                                               unsigned short* __restrict__ xt,
                                               float2* __restrict__ ixy) {
  __shared__ __align__(16) char smem[44112];
  // [0,34816): xt tile 128 rows x 272 B ; [34816,44032): w_off ; [44032,...): b_off
  const int tid = threadIdx.x;
  if (blockIdx.x >= 392) {
    const int i = (blockIdx.x - 392) * 128 + tid;   // 1152 blocks * 128 = 147456 f4
    float4 v = wconv[i];
    ushort4 o;
    o.x = f2bf(v.x); o.y = f2bf(v.y); o.z = f2bf(v.z); o.w = f2bf(v.w);
    wb[i] = o;
    return;
  }
  float* lwoff = (float*)(smem + 34816);
  float* lboff = (float*)(smem + 44032);
  const int m0 = blockIdx.x * 128;                  // 392*128 = 50176 exact
  const int m = m0 + tid;
  const int bb = m / HWN;
  const int hw = m - bb * HWN;
  const int h = hw / WN;
  const int w = hw - h * WN;

  for (int i = tid; i < DN * CN / 4; i += 128)
    ((float4*)lwoff)[i] = ((const float4*)w_off)[i];
  if (tid < DN) lboff[tid] = b_off[tid];
  __syncthreads();

  const float* xp = x + (size_t)bb * CN * HWN + hw;   // per-thread column base
  float acc[DN];
#pragma unroll
  for (int d = 0; d < DN; ++d) acc[d] = lboff[d];

  // c-loop in chunks of 8: coalesced global dword loads (lane = hw), pack to
  // bf16 uint4, ONE ds_write_b128 per chunk (row stride 272 B, 16B-aligned ->
  // structural-minimum LDS cost), dot vs broadcast w_off float4 pairs
  // (identical accumulation order to R0's k_offsets).
#pragma unroll
  for (int j = 0; j < 16; ++j) {
    float xf[8];
#pragma unroll
    for (int q = 0; q < 8; ++q) xf[q] = xp[(size_t)(j * 8 + q) * HWN];
    unsigned short ov[8];
#pragma unroll
    for (int q = 0; q < 8; ++q) ov[q] = f2bf(xf[q]);
    *(uint4*)(smem + tid * 272 + j * 16) = *(const uint4*)ov;
#pragma unroll
    for (int d = 0; d < DN; ++d) {
      float4 w0 = *(const float4*)(lwoff + d * CN + j * 8);      // uniform -> broadcast
      float4 w1 = *(const float4*)(lwoff + d * CN + j * 8 + 4);
      acc[d] += xf[0] * w0.x + xf[1] * w0.y + xf[2] * w0.z + xf[3] * w0.w
              + xf[4] * w1.x + xf[5] * w1.y + xf[6] * w1.z + xf[7] * w1.w;
    }
  }
  __syncthreads();   // tile complete

  // bulk xt write: 2048 16B chunks = 128 rows x 16; consecutive tid ->
  // consecutive global 16 B -> 1 KiB/wave fully coalesced.
#pragma unroll
  for (int p = 0; p < 16; ++p) {
    const int idx = p * 128 + tid;
    const int mr = idx >> 4, c16 = idx & 15;
    uint4 v = *(const uint4*)(smem + mr * 272 + c16 * 16);
    *(uint4*)(xt + (size_t)(m0 + mr) * CN + c16 * 8) = v;
  }

  const float scale = 2.0f / 56.0f;
  const float bx = (2.0f * w + 1.0f) / (float)WN - 1.0f;
  const float by = (2.0f * h + 1.0f) / (float)HN - 1.0f;
#pragma unroll
  for (int f = 0; f < FN; ++f) {
    float gx = bx + acc[2 * f] * scale;
    float gy = by + acc[2 * f + 1] * scale;
    float ixv = ((gx + 1.0f) * (float)WN - 1.0f) * 0.5f;
    float iyv = ((gy + 1.0f) * (float)HN - 1.0f) * 0.5f;
    ixy[(size_t)m * FN + f] = make_float2(ixv, iyv);
  }
}

// ---------------- Phase 2: bilinear sample (bf16 in) -> S bf16 [M, K] ----------
// mf-major thread order: all 9 taps of a pixel in the same block -> corner reads
// overlap in L1/L2.
__global__ void k_sample(const unsigned short* __restrict__ xt, const float2* __restrict__ ixy,
                         unsigned short* __restrict__ S) {
  const int g = blockIdx.x * 256 + threadIdx.x;  // 50176*9*8 = 14112*256 exact
  const int cc = g & 7;           // 16-channel chunk
  const int mf = g >> 3;          // m*9 + f
  const int m = mf / FN;
  const int f = mf - m * FN;
  const int b = m / HWN;

  const float2 p = ixy[mf];
  const float ix = p.x, iy = p.y;
  const float x0f = floorf(ix), y0f = floorf(iy);
  const float wx1 = ix - x0f, wy1 = iy - y0f;
  const float wx0 = 1.0f - wx1, wy0 = 1.0f - wy1;
  const int x0 = (int)x0f, y0 = (int)y0f;
  const int x1 = x0 + 1, y1 = y0 + 1;
  const bool vx0 = (x0 >= 0) & (x0 < WN), vx1 = (x1 >= 0) & (x1 < WN);
  const bool vy0 = (y0 >= 0) & (y0 < HN), vy1 = (y1 >= 0) & (y1 < HN);
  const float w00 = wy0 * wx0 * ((vy0 & vx0) ? 1.0f : 0.0f);
  const float w01 = wy0 * wx1 * ((vy0 & vx1) ? 1.0f : 0.0f);
  const float w10 = wy1 * wx0 * ((vy1 & vx0) ? 1.0f : 0.0f);
  const float w11 = wy1 * wx1 * ((vy1 & vx1) ? 1.0f : 0.0f);
  const int x0c = min(max(x0, 0), WN - 1), x1c = min(max(x1, 0), WN - 1);
  const int y0c = min(max(y0, 0), HN - 1), y1c = min(max(y1, 0), HN - 1);

  const unsigned short* bp = xt + (size_t)b * HWN * CN + cc * 16;
  const bf16x8* p00 = (const bf16x8*)(bp + (size_t)(y0c * WN + x0c) * CN);
  const bf16x8* p01 = (const bf16x8*)(bp + (size_t)(y0c * WN + x1c) * CN);
  const bf16x8* p10 = (const bf16x8*)(bp + (size_t)(y1c * WN + x0c) * CN);
  const bf16x8* p11 = (const bf16x8*)(bp + (size_t)(y1c * WN + x1c) * CN);
  bf16x8 a0 = p00[0], a1 = p00[1];
  bf16x8 b0 = p01[0], b1 = p01[1];
  bf16x8 c0 = p10[0], c1 = p10[1];
  bf16x8 d0 = p11[0], d1 = p11[1];

  unsigned short ov[16];
#pragma unroll
  for (int q = 0; q < 8; ++q) {
    float lo = w00 * (float)a0[q] + w01 * (float)b0[q] + w10 * (float)c0[q] + w11 * (float)d0[q];
    float hi = w00 * (float)a1[q] + w01 * (float)b1[q] + w10 * (float)c1[q] + w11 * (float)d1[q];
    ov[q] = f2bf(lo);
    ov[q + 8] = f2bf(hi);
  }
  uint4* dst = (uint4*)(S + (size_t)m * KN + f * CN + cc * 16);
  dst[0] = *(const uint4*)(ov);
  dst[1] = *(const uint4*)(ov + 8);
}

// ---------------- Phase 3: GEMM  out[o,m] = sum_k Wb[o,k]*S[m,k] + bias[o] ------
// 128x128 tile, BK=64, XOR-swizzled LDS, single-buffer (best measured: 81.6 us),
// XCD-aware 1-D grid: the 4 o-tiles of one p-tile land on the SAME XCD.
__global__ __launch_bounds__(256) void k_gemm(const unsigned short* __restrict__ Wb,
                                              const unsigned short* __restrict__ S,
                                              const float* __restrict__ bias,
                                              float* __restrict__ out) {
  __shared__ __align__(16) char smem[32768];
  unsigned short* lw = (unsigned short*)smem;            // 16 KB: W tile [128 o][64 k]
  unsigned short* ls = (unsigned short*)(smem + 16384);  // 16 KB: S tile [128 m][64 k]
  const int tid = threadIdx.x;
  const int wave = tid >> 6;
  const int lane = tid & 63;
  const int quad = lane >> 4;
  const int r16 = lane & 15;
  const int bid = blockIdx.x;                 // 1568 = 4 o-tiles x 392 p-tiles
  const int ot = (bid >> 3) & 3;
  const int pt = (bid & 7) + ((bid >> 5) << 3);
  const int o0 = ot * 128;
  const int p0 = pt * 128;
  const int wrow = wave >> 1;       // o-dim wave
  const int wcol = wave & 1;        // m-dim wave

  f32x4 acc[4][4];
#pragma unroll
  for (int i = 0; i < 4; ++i)
#pragma unroll
    for (int j = 0; j < 4; ++j) acc[i][j] = (f32x4){0.f, 0.f, 0.f, 0.f};

  // staging: slot s = r*256 + tid -> LDS 16B chunk s; row = s/8, chunk-in-row = s%8.
  // swizzle: LDS[row][ch] holds global chunk (ch ^ (row&7)).
  const int row0 = tid >> 3;                              // 0..31
  const int swc = (((tid & 7) ^ (row0 & 7))) * 8;         // swizzled col (shorts)
  const unsigned short* gw = Wb + (size_t)(o0 + row0) * KN + swc;
  const unsigned short* gs = S + (size_t)(p0 + row0) * KN + swc;
  unsigned short* lwd = lw + wave * 512;   // wave-uniform LDS base (shorts)
  unsigned short* lsd = ls + wave * 512;

  // reader: fragment row = wrow*64+i*16+r16 (row&7 == r16&7),
  // wanted chunk c = quad + h*4 -> LDS chunk c ^ (r16&7)
  const int rsw = r16 & 7;
  const int ch0 = (quad ^ rsw) * 8;                 // h=0 chunk offset (shorts)
  const int ch1 = ((quad ^ rsw) ^ 4) * 8;           // h=1
  const unsigned short* aw = lw + (wrow * 64 + r16) * 64;
  const unsigned short* bs = ls + (wcol * 64 + r16) * 64;

  for (int kt = 0; kt < KN / 64; ++kt) {
#pragma unroll
    for (int r = 0; r < 4; ++r) {
      gload_lds16(gw + (size_t)r * 32 * KN, lwd + r * 2048);
      gload_lds16(gs + (size_t)r * 32 * KN, lsd + r * 2048);
    }
    gw += 64; gs += 64;
    __syncthreads();
#pragma unroll
    for (int h = 0; h < 2; ++h) {
      const int ch = h ? ch1 : ch0;
      bf16x8 afr[4], bfr[4];
#pragma unroll
      for (int i = 0; i < 4; ++i) afr[i] = *(const bf16x8*)(aw + i * 16 * 64 + ch);
#pragma unroll
      for (int j = 0; j < 4; ++j) bfr[j] = *(const bf16x8*)(bs + j * 16 * 64 + ch);
#pragma unroll
      for (int i = 0; i < 4; ++i)
#pragma unroll
        for (int j = 0; j < 4; ++j)
          acc[i][j] = __builtin_amdgcn_mfma_f32_16x16x32_bf16(afr[i], bfr[j], acc[i][j], 0, 0, 0);
    }
    __syncthreads();
  }

  // Epilogue: stage 64 o-rows x 128 p-cols fp32 in smem (32 KB), write full lines.
  // C/D layout: col(m)=r16, row(o)=quad*4+reg.
  float* lout = (float*)smem;
  for (int half = 0; half < 2; ++half) {
    __syncthreads();
    if (wrow == half) {
#pragma unroll
      for (int i = 0; i < 4; ++i) {
        const int orow = i * 16 + quad * 4;
#pragma unroll
        for (int j = 0; j < 4; ++j) {
          const int col = wcol * 64 + j * 16 + r16;
          lout[(orow + 0) * 128 + col] = acc[i][j][0];
          lout[(orow + 1) * 128 + col] = acc[i][j][1];
          lout[(orow + 2) * 128 + col] = acc[i][j][2];
          lout[(orow + 3) * 128 + col] = acc[i][j][3];
        }
      }
    }
    __syncthreads();
#pragma unroll
    for (int t = 0; t < 8; ++t) {
      const int idx = t * 256 + tid;        // 2048 float4s = 64 rows x 32 f4/row
      const int orow = idx >> 5;
      const int c4 = idx & 31;
      float4 v = ((const float4*)lout)[idx];
      const int o = o0 + half * 64 + orow;
      const float bv = bias[o];
      v.x += bv; v.y += bv; v.z += bv; v.w += bv;
      const int p = p0 + c4 * 4;
      const int bidx = p / HWN;             // 3136 % 4 == 0 -> float4 never straddles b
      const int hw = p - bidx * HWN;
      *(float4*)(out + (size_t)bidx * ON * HWN + (size_t)o * HWN + hw) = v;
    }
  }
}

extern "C" void kernel_launch(void* const* d_in, const int* in_sizes, int n_in,
                              void* d_out, int out_size, void* d_ws, size_t ws_size,
                              hipStream_t stream) {
  const float* x = (const float*)d_in[0];       // [16,128,56,56]
  const float* w_off = (const float*)d_in[1];   // [18,128]
  const float* b_off = (const float*)d_in[2];   // [18]
  const float* w_conv = (const float*)d_in[3];  // [512,1152]
  const float* b_conv = (const float*)d_in[4];  // [512]
  float* out = (float*)d_out;                   // [16,512,56,56] fp32

  // workspace layout (16B aligned):
  //   xt  : bf16 [B,HW,C]      12,845,056 B @ 0
  //   S   : bf16 [M,K]        115,605,504 B @ 12,845,056
  //   Wb  : bf16 [512,1152]     1,179,648 B @ 128,450,560
  //   ixy : float2 [M,F]        3,612,672 B @ 129,630,208   (total ~133.2 MB)
  char* ws = (char*)d_ws;
  unsigned short* xt = (unsigned short*)(ws);
  unsigned short* S = (unsigned short*)(ws + 12845056);
  unsigned short* Wb = (unsigned short*)(ws + 128450560);
  float2* ixy = (float2*)(ws + 129630208);

  k_prep2<<<dim3(1544), 128, 0, stream>>>(x, w_off, b_off, (const float4*)w_conv,
                                          (ushort4*)Wb, xt, ixy);
  k_sample<<<dim3(14112), 256, 0, stream>>>(xt, ixy, S);
  k_gemm<<<dim3(1568), 256, 0, stream>>>(Wb, S, b_conv, out);
}